// Round 8
// baseline (428.825 us; speedup 1.0000x reference)
//
#include <hip/hip_runtime.h>
#include <hip/hip_bf16.h>
#include <stdint.h>

// SparseMoE top-2/8, N=8192, D=1024, H=2048, fp32 in/out.
// R8: GEMMs -> 128x256 tile, 3-buffer LDS rotation, 2-K-tile prefetch,
//     ONE barrier + ONE counted vmcnt(6) per K-tile (never drain in loop).
//     Staging tile t+2 targets buf[(t+2)%3] which was freed at the t-top
//     barrier (distinct from read buf t%3 and in-flight buf (t+1)%3) -> no
//     write hazard, no second barrier. T2 both-sides swizzle + T5 setprio.
//     Router/plan (atomic-free) and combine unchanged from R6.

#define N_TOK 8192
#define D_DIM 1024
#define H_DIM 2048
#define N_EXP 8
#define N_ASSIGN (N_TOK * 2)

typedef __attribute__((ext_vector_type(8))) short short8;   // bf16x8
typedef __attribute__((ext_vector_type(4))) float f32x4;    // MFMA acc frag

__device__ __forceinline__ unsigned short f2bf(float f) {
  union { float f; unsigned int u; } v; v.f = f;
  unsigned int r = v.u + 0x7fffu + ((v.u >> 16) & 1u);  // RTNE
  return (unsigned short)(r >> 16);
}
__device__ __forceinline__ float bf2f(unsigned short u) {
  union { float f; unsigned int u; } v; v.u = ((unsigned int)u) << 16; return v.f;
}
__device__ __forceinline__ short8 pack8(float4 a, float4 b) {
  short8 o;
  o[0] = (short)f2bf(a.x); o[1] = (short)f2bf(a.y);
  o[2] = (short)f2bf(a.z); o[3] = (short)f2bf(a.w);
  o[4] = (short)f2bf(b.x); o[5] = (short)f2bf(b.y);
  o[6] = (short)f2bf(b.z); o[7] = (short)f2bf(b.w);
  return o;
}
__device__ __forceinline__ void gload_lds16(const void* g, void* l) {
  __builtin_amdgcn_global_load_lds((const __attribute__((address_space(1))) void*)g,
                                   (__attribute__((address_space(3))) void*)l, 16, 0, 0);
}

// ---------- K1: router (blocks [0,2048)) + wgu convert (blocks [2048,18432))
__global__ __launch_bounds__(256) void router_prep_kernel(
    const float* __restrict__ x, const float* __restrict__ rw,
    const float* __restrict__ rb,
    const float* __restrict__ wg, const float* __restrict__ wu,
    unsigned short* __restrict__ xb, unsigned short* __restrict__ wgu,
    int2* __restrict__ tiidx, float2* __restrict__ tiw) {
  int b = blockIdx.x;
  int tid = threadIdx.x;
  if (b >= 2048) {
    int idx = b - 2048;                      // 0..16383
    int up = idx >> 13;                      // 0 = gate, 1 = up
    size_t i = (((size_t)(idx & 8191)) * 256 + tid) * 8;
    const float* src = up ? wu : wg;
    float4 a = *(const float4*)(src + i);
    float4 c = *(const float4*)(src + i + 4);
    int j = (int)(i >> 10);                  // source row = e*H + jj
    int e = j >> 11;
    int jj = j & (H_DIM - 1);
    int n = ((jj >> 4) << 5) + (up ? 16 : 0) + (jj & 15);
    size_t di = (((size_t)(e << 12) + n) << 10) + (i & 1023);
    *(short8*)(wgu + di) = pack8(a, c);
    return;
  }

  __shared__ float sw[N_EXP][D_DIM];          // 32 KB router weights
  for (int i = tid * 4; i < N_EXP * D_DIM; i += 1024)
    *(float4*)&sw[0][i] = *(const float4*)(rw + i);
  __syncthreads();

  int wave = tid >> 6, lane = tid & 63;
  int t = b * 4 + wave;
  const float2* xr = (const float2*)(x + (size_t)t * D_DIM);
  float2 xs[8];
#pragma unroll
  for (int j = 0; j < 8; j++) xs[j] = xr[lane + 64 * j];
  unsigned int* xbo = (unsigned int*)(xb + (size_t)t * D_DIM);
#pragma unroll
  for (int j = 0; j < 8; j++) {
    unsigned int pk = ((unsigned int)f2bf(xs[j].y) << 16) | (unsigned int)f2bf(xs[j].x);
    xbo[lane + 64 * j] = pk;
  }

  float logit[N_EXP];
#pragma unroll
  for (int e = 0; e < N_EXP; e++) {
    float acc = 0.f;
    const float2* swe = (const float2*)sw[e];
#pragma unroll
    for (int j = 0; j < 8; j++) {
      float2 w2 = swe[lane + 64 * j];
      acc += xs[j].x * w2.x + xs[j].y * w2.y;
    }
#pragma unroll
    for (int off = 32; off; off >>= 1) acc += __shfl_xor(acc, off);
    logit[e] = acc + rb[e];
  }
  if (lane == 0) {
    float m = logit[0];
#pragma unroll
    for (int e = 1; e < N_EXP; e++) m = fmaxf(m, logit[e]);
    float p[N_EXP], S = 0.f;
#pragma unroll
    for (int e = 0; e < N_EXP; e++) { p[e] = expf(logit[e] - m); S += p[e]; }
#pragma unroll
    for (int e = 0; e < N_EXP; e++) p[e] /= S;
    int i1 = 0; float v1 = p[0];
#pragma unroll
    for (int e = 1; e < N_EXP; e++) if (p[e] > v1) { v1 = p[e]; i1 = e; }
    int i2 = -1; float v2 = -1.f;
#pragma unroll
    for (int e = 0; e < N_EXP; e++) if (e != i1 && p[e] > v2) { v2 = p[e]; i2 = e; }
    float inv = 1.f / (v1 + v2 + 1e-9f);
    tiidx[t] = make_int2(i1, i2);
    tiw[t] = make_float2(v1 * inv, v2 * inv);
  }
}

// ---------- K2: plan = histogram + scan + slot assignment, one block --------
__global__ __launch_bounds__(256) void plan_kernel(
    const int2* __restrict__ tiidx, int* __restrict__ cnt,
    int* __restrict__ off, int* __restrict__ assign, int2* __restrict__ trows) {
  __shared__ int sh[256][N_EXP + 1];
  __shared__ int soff[N_EXP];
  int tid = threadIdx.x;
  int t0 = tid * 32;

#pragma unroll
  for (int e = 0; e < N_EXP; e++) sh[tid][e] = 0;
  for (int i = 0; i < 32; i++) {
    int2 te = tiidx[t0 + i];
    sh[tid][te.x]++;
    sh[tid][te.y]++;
  }
  int oc[N_EXP];
#pragma unroll
  for (int e = 0; e < N_EXP; e++) oc[e] = sh[tid][e];
  __syncthreads();

  for (int s = 1; s < 256; s <<= 1) {
    int v[N_EXP];
#pragma unroll
    for (int e = 0; e < N_EXP; e++) v[e] = (tid >= s) ? sh[tid - s][e] : 0;
    __syncthreads();
#pragma unroll
    for (int e = 0; e < N_EXP; e++) sh[tid][e] += v[e];
    __syncthreads();
  }

  int ex[N_EXP];
#pragma unroll
  for (int e = 0; e < N_EXP; e++) ex[e] = sh[tid][e] - oc[e];
  if (tid == 0) {
    int a = 0;
    for (int e = 0; e < N_EXP; e++) {
      int tot = sh[255][e];
      soff[e] = a; off[e] = a; cnt[e] = tot; a += tot;
    }
    off[N_EXP] = a;
  }
  __syncthreads();
#pragma unroll
  for (int e = 0; e < N_EXP; e++) sh[tid][e] = ex[e];
  __syncthreads();

  for (int i = 0; i < 32; i++) {
    int t = t0 + i;
    int2 te = tiidx[t];
    int r1 = soff[te.x] + sh[tid][te.x]++;
    int r2 = soff[te.y] + sh[tid][te.y]++;
    assign[r1] = t;
    assign[r2] = t;
    trows[t] = make_int2(r1, r2);
  }
}

// ---------- K3: GEMM1 128x256 / 3-buffer / 1-barrier-per-K-tile -------------
// z<8: fused gate+up; z==8: wd fp32->bf16 convert slice.
__global__ __launch_bounds__(512, 2) void gemm_gateup(
    const unsigned short* __restrict__ xb,    // [N_TOK, D] bf16
    const unsigned short* __restrict__ wgu,   // [E*4096, D] bf16 interleaved
    const float* __restrict__ wd,             // [E*D, H] fp32 (convert slice)
    unsigned short* __restrict__ wdb,         // [E*D, H] bf16 out
    const int* __restrict__ cnt, const int* __restrict__ off,
    const int* __restrict__ assign,
    unsigned short* __restrict__ hbuf) {      // [N_ASSIGN, H] bf16
  int tid = threadIdx.x;
  if (blockIdx.z == 8) {
    // wd convert: 16x64=1024 blocks x 512 threads x 32 floats
    size_t b0 = ((size_t)(blockIdx.x + 16 * blockIdx.y)) * 16384;
#pragma unroll
    for (int it = 0; it < 4; it++) {
      size_t i = b0 + ((size_t)it * 512 + tid) * 8;
      float4 a = *(const float4*)(wd + i);
      float4 c = *(const float4*)(wd + i + 4);
      *(short8*)(wdb + i) = pack8(a, c);
    }
    return;
  }
  int e = blockIdx.z;
  int nrows = cnt[e];
  int row0 = blockIdx.y * 128;
  if (row0 >= nrows) return;
  int col0 = blockIdx.x * 256;                // in [0, 4096)
  int base = off[e];

  __shared__ unsigned short sA[3][128][64];   // 48 KB
  __shared__ unsigned short sB[3][256][64];   // 96 KB

  int srow = tid >> 3;                        // 0..63
  int dst8 = (tid & 7) * 8;                   // linear LDS chunk (gload req)
  int src8 = ((tid & 7) ^ (srow & 7)) * 8;    // pre-swizzled global column

  const unsigned short* asrc[2];
#pragma unroll
  for (int i = 0; i < 2; i++) {
    int r = row0 + srow + 64 * i;
    int tok = (r < nrows) ? assign[base + r] : assign[base];
    asrc[i] = xb + (size_t)tok * D_DIM + src8;
  }
  const unsigned short* bsrc[4];
#pragma unroll
  for (int i = 0; i < 4; i++) {
    int wrow = (e << 12) + col0 + srow + 64 * i;
    bsrc[i] = wgu + (size_t)wrow * D_DIM + src8;
  }

  int wid = tid >> 6;                         // 0..7
  int wr = wid >> 2;                          // 0..1  (M: 2 x 64 rows)
  int wc = wid & 3;                           // 0..3  (N: 4 x 64 cols)
  int lane = tid & 63;
  int fr = lane & 15;
  int fq = lane >> 4;
  int fk = fq * 8;
  int rx = (fr & 7) * 8;                      // read-side swizzle XOR

  f32x4 acc[4][4];
#pragma unroll
  for (int a = 0; a < 4; a++)
#pragma unroll
    for (int b = 0; b < 4; b++) acc[a][b] = (f32x4){0.f, 0.f, 0.f, 0.f};

#define STAGE(bf, k0)                                                       \
  {                                                                         \
    _Pragma("unroll")                                                       \
    for (int i = 0; i < 2; i++)                                             \
      gload_lds16(asrc[i] + (k0), &sA[bf][srow + 64 * i][dst8]);            \
    _Pragma("unroll")                                                       \
    for (int i = 0; i < 4; i++)                                             \
      gload_lds16(bsrc[i] + (k0), &sB[bf][srow + 64 * i][dst8]);            \
  }
#define COMPUTE(bf)                                                         \
  _Pragma("unroll")                                                         \
  for (int ks = 0; ks < 2; ks++) {                                          \
    short8 af[4], bq[4];                                                    \
    int c = (ks * 32 + fk) ^ rx;                                            \
    _Pragma("unroll")                                                       \
    for (int mb = 0; mb < 4; mb++)                                          \
      af[mb] = *(const short8*)&sA[bf][wr * 64 + mb * 16 + fr][c];          \
    _Pragma("unroll")                                                       \
    for (int nb = 0; nb < 4; nb++)                                          \
      bq[nb] = *(const short8*)&sB[bf][wc * 64 + nb * 16 + fr][c];          \
    __builtin_amdgcn_s_setprio(1);                                          \
    _Pragma("unroll")                                                       \
    for (int mb = 0; mb < 4; mb++)                                          \
      _Pragma("unroll")                                                     \
      for (int nb = 0; nb < 4; nb++)                                        \
        acc[mb][nb] = __builtin_amdgcn_mfma_f32_16x16x32_bf16(              \
            af[mb], bq[nb], acc[mb][nb], 0, 0, 0);                          \
    __builtin_amdgcn_s_setprio(0);                                          \
  }

  // NT = 16 K-tiles of 64. 3 buffers, 2-tile prefetch.
  // In-flight ledger: prologue 12; loop-top vmcnt(6) retires exactly tile t
  // (t+1's 6 stay in flight across the barrier); body restores to 12.
  STAGE(0, 0);
  STAGE(1, 64);
  for (int t = 0; t < 15; ++t) {
    asm volatile("s_waitcnt vmcnt(6)" ::: "memory");
    __builtin_amdgcn_sched_barrier(0);
    __builtin_amdgcn_s_barrier();             // tile t ready; buf[(t+2)%3] free
    __builtin_amdgcn_sched_barrier(0);
    if (t < 14) { int nb3 = (t + 2) % 3; STAGE(nb3, (t + 2) * 64); }
    COMPUTE(t % 3);
  }
  asm volatile("s_waitcnt vmcnt(0)" ::: "memory");
  __builtin_amdgcn_sched_barrier(0);
  __builtin_amdgcn_s_barrier();
  __builtin_amdgcn_sched_barrier(0);
  COMPUTE(0);                                 // tile 15 -> buf 15%3 = 0
#undef STAGE
#undef COMPUTE

  int rowlim = nrows - row0;
#pragma unroll
  for (int mb = 0; mb < 4; mb++)
#pragma unroll
    for (int r = 0; r < 4; r++) {
      int lrow = wr * 64 + mb * 16 + fq * 4 + r;
      if (lrow < rowlim) {
        size_t hrow = (size_t)(base + row0 + lrow);
#pragma unroll
        for (int nbp = 0; nbp < 2; nbp++) {
          float g = acc[mb][2 * nbp][r], u = acc[mb][2 * nbp + 1][r];
          float hv = g / (1.f + __expf(-g)) * u;     // silu(g)*u
          int hcol = (col0 >> 1) + wc * 32 + nbp * 16 + fr;
          hbuf[hrow * H_DIM + hcol] = f2bf(hv);
        }
      }
    }
}

// ---------- K4: GEMM2 e_out = h @ Wd^T, same 3-buffer schedule, NT=32 -------
__global__ __launch_bounds__(512, 2) void gemm_down(
    const unsigned short* __restrict__ hbuf,  // [N_ASSIGN, H] bf16
    const unsigned short* __restrict__ wd,    // [E*D, H] bf16
    const int* __restrict__ cnt, const int* __restrict__ off,
    unsigned short* __restrict__ eo) {        // [N_ASSIGN, D] bf16
  int e = blockIdx.z;
  int nrows = cnt[e];
  int row0 = blockIdx.y * 128;
  if (row0 >= nrows) return;
  int col0 = blockIdx.x * 256;                // in [0, 1024)
  int base = off[e];

  __shared__ unsigned short sA[3][128][64];
  __shared__ unsigned short sB[3][256][64];

  int tid = threadIdx.x;
  int srow = tid >> 3;
  int dst8 = (tid & 7) * 8;
  int src8 = ((tid & 7) ^ (srow & 7)) * 8;

  const unsigned short* asrc[2];
#pragma unroll
  for (int i = 0; i < 2; i++) {
    int r = row0 + srow + 64 * i;
    int hrow = base + ((r < nrows) ? r : 0);
    asrc[i] = hbuf + (size_t)hrow * H_DIM + src8;
  }
  const unsigned short* bsrc[4];
#pragma unroll
  for (int i = 0; i < 4; i++) {
    int wrow = e * D_DIM + col0 + srow + 64 * i;
    bsrc[i] = wd + (size_t)wrow * H_DIM + src8;
  }

  int wid = tid >> 6;
  int wr = wid >> 2;
  int wc = wid & 3;
  int lane = tid & 63;
  int fr = lane & 15;
  int fq = lane >> 4;
  int fk = fq * 8;
  int rx = (fr & 7) * 8;

  f32x4 acc[4][4];
#pragma unroll
  for (int a = 0; a < 4; a++)
#pragma unroll
    for (int b = 0; b < 4; b++) acc[a][b] = (f32x4){0.f, 0.f, 0.f, 0.f};

#define STAGE(bf, k0)                                                       \
  {                                                                         \
    _Pragma("unroll")                                                       \
    for (int i = 0; i < 2; i++)                                             \
      gload_lds16(asrc[i] + (k0), &sA[bf][srow + 64 * i][dst8]);            \
    _Pragma("unroll")                                                       \
    for (int i = 0; i < 4; i++)                                             \
      gload_lds16(bsrc[i] + (k0), &sB[bf][srow + 64 * i][dst8]);            \
  }
#define COMPUTE(bf)                                                         \
  _Pragma("unroll")                                                         \
  for (int ks = 0; ks < 2; ks++) {                                          \
    short8 af[4], bq[4];                                                    \
    int c = (ks * 32 + fk) ^ rx;                                            \
    _Pragma("unroll")                                                       \
    for (int mb = 0; mb < 4; mb++)                                          \
      af[mb] = *(const short8*)&sA[bf][wr * 64 + mb * 16 + fr][c];          \
    _Pragma("unroll")                                                       \
    for (int nb = 0; nb < 4; nb++)                                          \
      bq[nb] = *(const short8*)&sB[bf][wc * 64 + nb * 16 + fr][c];          \
    __builtin_amdgcn_s_setprio(1);                                          \
    _Pragma("unroll")                                                       \
    for (int mb = 0; mb < 4; mb++)                                          \
      _Pragma("unroll")                                                     \
      for (int nb = 0; nb < 4; nb++)                                        \
        acc[mb][nb] = __builtin_amdgcn_mfma_f32_16x16x32_bf16(              \
            af[mb], bq[nb], acc[mb][nb], 0, 0, 0);                          \
    __builtin_amdgcn_s_setprio(0);                                          \
  }

  // NT = 32 K-tiles of 64.
  STAGE(0, 0);
  STAGE(1, 64);
  for (int t = 0; t < 31; ++t) {
    asm volatile("s_waitcnt vmcnt(6)" ::: "memory");
    __builtin_amdgcn_sched_barrier(0);
    __builtin_amdgcn_s_barrier();
    __builtin_amdgcn_sched_barrier(0);
    if (t < 30) { int nb3 = (t + 2) % 3; STAGE(nb3, (t + 2) * 64); }
    COMPUTE(t % 3);
  }
  asm volatile("s_waitcnt vmcnt(0)" ::: "memory");
  __builtin_amdgcn_sched_barrier(0);
  __builtin_amdgcn_s_barrier();
  __builtin_amdgcn_sched_barrier(0);
  COMPUTE(1);                                 // tile 31 -> buf 31%3 = 1
#undef STAGE
#undef COMPUTE

  int rowlim = nrows - row0;
#pragma unroll
  for (int mb = 0; mb < 4; mb++)
#pragma unroll
    for (int r = 0; r < 4; r++) {
      int lrow = wr * 64 + mb * 16 + fq * 4 + r;
      if (lrow < rowlim) {
        size_t orow = (size_t)(base + row0 + lrow);
#pragma unroll
        for (int nb = 0; nb < 4; nb++)
          eo[orow * D_DIM + col0 + wc * 64 + nb * 16 + fr] = f2bf(acc[mb][nb][r]);
      }
    }
}

// ---------- K5: combine out[t] = w1*eo[r1] + w2*eo[r2] -----------------------
__global__ __launch_bounds__(256) void combine_kernel(
    const unsigned short* __restrict__ eo, const int2* __restrict__ trows,
    const float2* __restrict__ tiw, float* __restrict__ out) {
  int t = blockIdx.x * 2 + (threadIdx.x >> 7);
  int l = threadIdx.x & 127;
  int c = l * 8;
  int2 r = trows[t];
  float2 w = tiw[t];
  short8 a = *(const short8*)&eo[(size_t)r.x * D_DIM + c];
  short8 b = *(const short8*)&eo[(size_t)r.y * D_DIM + c];
  float4 o0, o1;
  o0.x = w.x * bf2f((unsigned short)a[0]) + w.y * bf2f((unsigned short)b[0]);
  o0.y = w.x * bf2f((unsigned short)a[1]) + w.y * bf2f((unsigned short)b[1]);
  o0.z = w.x * bf2f((unsigned short)a[2]) + w.y * bf2f((unsigned short)b[2]);
  o0.w = w.x * bf2f((unsigned short)a[3]) + w.y * bf2f((unsigned short)b[3]);
  o1.x = w.x * bf2f((unsigned short)a[4]) + w.y * bf2f((unsigned short)b[4]);
  o1.y = w.x * bf2f((unsigned short)a[5]) + w.y * bf2f((unsigned short)b[5]);
  o1.z = w.x * bf2f((unsigned short)a[6]) + w.y * bf2f((unsigned short)b[6]);
  o1.w = w.x * bf2f((unsigned short)a[7]) + w.y * bf2f((unsigned short)b[7]);
  *(float4*)&out[(size_t)t * D_DIM + c] = o0;
  *(float4*)&out[(size_t)t * D_DIM + c + 4] = o1;
}

extern "C" void kernel_launch(void* const* d_in, const int* in_sizes, int n_in,
                              void* d_out, int out_size, void* d_ws, size_t ws_size,
                              hipStream_t stream) {
  const float* x  = (const float*)d_in[0];
  const float* rw = (const float*)d_in[1];
  const float* rb = (const float*)d_in[2];
  const float* wg = (const float*)d_in[3];
  const float* wu = (const float*)d_in[4];
  const float* wd = (const float*)d_in[5];
  float* out = (float*)d_out;

  char* ws = (char*)d_ws;
  size_t o = 0;
  auto alloc = [&](size_t b) { char* p = ws + o; o += (b + 255) & ~(size_t)255; return p; };
  unsigned short* xb  = (unsigned short*)alloc((size_t)N_TOK * D_DIM * 2);           // 16.8 MB
  unsigned short* wgu = (unsigned short*)alloc((size_t)N_EXP * 4096 * D_DIM * 2);    // 67.1 MB
  unsigned short* wdb = (unsigned short*)alloc((size_t)N_EXP * D_DIM * H_DIM * 2);   // 33.6 MB
  unsigned short* hb  = (unsigned short*)alloc((size_t)N_ASSIGN * H_DIM * 2);        // 67.1 MB
  unsigned short* eob = (unsigned short*)alloc((size_t)N_ASSIGN * D_DIM * 2);        // 33.6 MB
  int*    assign = (int*)alloc(N_ASSIGN * 4);
  int2*   tiidx  = (int2*)alloc(N_TOK * 8);
  float2* tiw    = (float2*)alloc(N_TOK * 8);
  int2*   trows  = (int2*)alloc(N_TOK * 8);
  int*    cnt    = (int*)alloc(64);
  int*    off    = (int*)alloc(64);

  router_prep_kernel<<<2048 + 16384, 256, 0, stream>>>(
      x, rw, rb, wg, wu, xb, wgu, tiidx, tiw);
  plan_kernel<<<1, 256, 0, stream>>>(tiidx, cnt, off, assign, trows);
  // z in [0,8): experts (128-row x 256-col tiles); z==8: wd convert slice.
  gemm_gateup<<<dim3(4096 / 256, N_TOK / 128, N_EXP + 1), 512, 0, stream>>>(
      xb, wgu, wd, wdb, cnt, off, assign, hb);
  gemm_down<<<dim3(D_DIM / 256, N_TOK / 128, N_EXP), 512, 0, stream>>>(
      hb, wdb, cnt, off, eob);
  combine_kernel<<<N_TOK / 2, 256, 0, stream>>>(eob, trows, tiw, out);
}

// Round 9
// 393.007 us; speedup vs baseline: 1.0911x; 1.0911x over previous
//
#include <hip/hip_runtime.h>
#include <hip/hip_bf16.h>
#include <stdint.h>

// SparseMoE top-2/8, N=8192, D=1024, H=2048, fp32 in/out.
// R9: consolidation. R7/R8 schedule rewrites both regressed (coarse phase
//     splits without the exact m201 interleave hurt, per m196). GEMMs locked
//     at the proven R6 structure (128^2, 2-phase dbuf, both-sides XOR swizzle,
//     ~650 TF = documented 2-phase ceiling). New: combine fused into
//     gemm_down's epilogue via deterministic atomicAdd (exactly 2
//     contributions per element onto zeroed out; IEEE add commutative ->
//     bitwise deterministic). Removes combine launch + eob buffer.

#define N_TOK 8192
#define D_DIM 1024
#define H_DIM 2048
#define N_EXP 8
#define N_ASSIGN (N_TOK * 2)
#define BM 128
#define BN 128
#define BK 64

typedef __attribute__((ext_vector_type(8))) short short8;   // bf16x8
typedef __attribute__((ext_vector_type(4))) float f32x4;    // MFMA acc frag

__device__ __forceinline__ unsigned short f2bf(float f) {
  union { float f; unsigned int u; } v; v.f = f;
  unsigned int r = v.u + 0x7fffu + ((v.u >> 16) & 1u);  // RTNE
  return (unsigned short)(r >> 16);
}
__device__ __forceinline__ float bf2f(unsigned short u) {
  union { float f; unsigned int u; } v; v.u = ((unsigned int)u) << 16; return v.f;
}
__device__ __forceinline__ short8 pack8(float4 a, float4 b) {
  short8 o;
  o[0] = (short)f2bf(a.x); o[1] = (short)f2bf(a.y);
  o[2] = (short)f2bf(a.z); o[3] = (short)f2bf(a.w);
  o[4] = (short)f2bf(b.x); o[5] = (short)f2bf(b.y);
  o[6] = (short)f2bf(b.z); o[7] = (short)f2bf(b.w);
  return o;
}
__device__ __forceinline__ void gload_lds16(const void* g, void* l) {
  __builtin_amdgcn_global_load_lds((const __attribute__((address_space(1))) void*)g,
                                   (__attribute__((address_space(3))) void*)l, 16, 0, 0);
}

// ---------- K1: router (blocks [0,2048)) + wgu convert (blocks [2048,18432))
__global__ __launch_bounds__(256) void router_prep_kernel(
    const float* __restrict__ x, const float* __restrict__ rw,
    const float* __restrict__ rb,
    const float* __restrict__ wg, const float* __restrict__ wu,
    unsigned short* __restrict__ xb, unsigned short* __restrict__ wgu,
    int2* __restrict__ tiidx, float2* __restrict__ tiw) {
  int b = blockIdx.x;
  int tid = threadIdx.x;
  if (b >= 2048) {
    int idx = b - 2048;                      // 0..16383
    int up = idx >> 13;                      // 0 = gate, 1 = up
    size_t i = (((size_t)(idx & 8191)) * 256 + tid) * 8;
    const float* src = up ? wu : wg;
    float4 a = *(const float4*)(src + i);
    float4 c = *(const float4*)(src + i + 4);
    int j = (int)(i >> 10);                  // source row = e*H + jj
    int e = j >> 11;
    int jj = j & (H_DIM - 1);
    int n = ((jj >> 4) << 5) + (up ? 16 : 0) + (jj & 15);
    size_t di = (((size_t)(e << 12) + n) << 10) + (i & 1023);
    *(short8*)(wgu + di) = pack8(a, c);
    return;
  }

  __shared__ float sw[N_EXP][D_DIM];          // 32 KB router weights
  for (int i = tid * 4; i < N_EXP * D_DIM; i += 1024)
    *(float4*)&sw[0][i] = *(const float4*)(rw + i);
  __syncthreads();

  int wave = tid >> 6, lane = tid & 63;
  int t = b * 4 + wave;
  const float2* xr = (const float2*)(x + (size_t)t * D_DIM);
  float2 xs[8];
#pragma unroll
  for (int j = 0; j < 8; j++) xs[j] = xr[lane + 64 * j];
  unsigned int* xbo = (unsigned int*)(xb + (size_t)t * D_DIM);
#pragma unroll
  for (int j = 0; j < 8; j++) {
    unsigned int pk = ((unsigned int)f2bf(xs[j].y) << 16) | (unsigned int)f2bf(xs[j].x);
    xbo[lane + 64 * j] = pk;
  }

  float logit[N_EXP];
#pragma unroll
  for (int e = 0; e < N_EXP; e++) {
    float acc = 0.f;
    const float2* swe = (const float2*)sw[e];
#pragma unroll
    for (int j = 0; j < 8; j++) {
      float2 w2 = swe[lane + 64 * j];
      acc += xs[j].x * w2.x + xs[j].y * w2.y;
    }
#pragma unroll
    for (int off = 32; off; off >>= 1) acc += __shfl_xor(acc, off);
    logit[e] = acc + rb[e];
  }
  if (lane == 0) {
    float m = logit[0];
#pragma unroll
    for (int e = 1; e < N_EXP; e++) m = fmaxf(m, logit[e]);
    float p[N_EXP], S = 0.f;
#pragma unroll
    for (int e = 0; e < N_EXP; e++) { p[e] = expf(logit[e] - m); S += p[e]; }
#pragma unroll
    for (int e = 0; e < N_EXP; e++) p[e] /= S;
    int i1 = 0; float v1 = p[0];
#pragma unroll
    for (int e = 1; e < N_EXP; e++) if (p[e] > v1) { v1 = p[e]; i1 = e; }
    int i2 = -1; float v2 = -1.f;
#pragma unroll
    for (int e = 0; e < N_EXP; e++) if (e != i1 && p[e] > v2) { v2 = p[e]; i2 = e; }
    float inv = 1.f / (v1 + v2 + 1e-9f);
    tiidx[t] = make_int2(i1, i2);
    tiw[t] = make_float2(v1 * inv, v2 * inv);
  }
}

// ---------- K2: plan = histogram + scan + slot assignment, one block --------
// emits: assign[row] = token, wassign[row] = combine weight for that row.
__global__ __launch_bounds__(256) void plan_kernel(
    const int2* __restrict__ tiidx, const float2* __restrict__ tiw,
    int* __restrict__ cnt, int* __restrict__ off,
    int* __restrict__ assign, float* __restrict__ wassign) {
  __shared__ int sh[256][N_EXP + 1];
  __shared__ int soff[N_EXP];
  int tid = threadIdx.x;
  int t0 = tid * 32;

#pragma unroll
  for (int e = 0; e < N_EXP; e++) sh[tid][e] = 0;
  for (int i = 0; i < 32; i++) {
    int2 te = tiidx[t0 + i];
    sh[tid][te.x]++;
    sh[tid][te.y]++;
  }
  int oc[N_EXP];
#pragma unroll
  for (int e = 0; e < N_EXP; e++) oc[e] = sh[tid][e];
  __syncthreads();

  for (int s = 1; s < 256; s <<= 1) {
    int v[N_EXP];
#pragma unroll
    for (int e = 0; e < N_EXP; e++) v[e] = (tid >= s) ? sh[tid - s][e] : 0;
    __syncthreads();
#pragma unroll
    for (int e = 0; e < N_EXP; e++) sh[tid][e] += v[e];
    __syncthreads();
  }

  int ex[N_EXP];
#pragma unroll
  for (int e = 0; e < N_EXP; e++) ex[e] = sh[tid][e] - oc[e];
  if (tid == 0) {
    int a = 0;
    for (int e = 0; e < N_EXP; e++) {
      int tot = sh[255][e];
      soff[e] = a; off[e] = a; cnt[e] = tot; a += tot;
    }
    off[N_EXP] = a;
  }
  __syncthreads();
#pragma unroll
  for (int e = 0; e < N_EXP; e++) sh[tid][e] = ex[e];
  __syncthreads();

  for (int i = 0; i < 32; i++) {
    int t = t0 + i;
    int2 te = tiidx[t];
    float2 w = tiw[t];
    int r1 = soff[te.x] + sh[tid][te.x]++;
    int r2 = soff[te.y] + sh[tid][te.y]++;
    assign[r1] = t;  wassign[r1] = w.x;
    assign[r2] = t;  wassign[r2] = w.y;
  }
}

// ---------- K3: GEMM1 (z<8) fused gate+up  |  wd convert (z==8) --------------
__global__ __launch_bounds__(256) void gemm_gateup(
    const unsigned short* __restrict__ xb,    // [N_TOK, D] bf16
    const unsigned short* __restrict__ wgu,   // [E*4096, D] bf16 interleaved
    const float* __restrict__ wd,             // [E*D, H] fp32 (convert slice)
    unsigned short* __restrict__ wdb,         // [E*D, H] bf16 out
    const int* __restrict__ cnt, const int* __restrict__ off,
    const int* __restrict__ assign,
    unsigned short* __restrict__ hbuf) {      // [N_ASSIGN, H] bf16
  int tid = threadIdx.x;
  if (blockIdx.z == 8) {
    size_t b0 = ((size_t)(blockIdx.x + 32 * blockIdx.y)) * 8192;
#pragma unroll
    for (int it = 0; it < 4; it++) {
      size_t i = b0 + ((size_t)it * 256 + tid) * 8;
      float4 a = *(const float4*)(wd + i);
      float4 c = *(const float4*)(wd + i + 4);
      *(short8*)(wdb + i) = pack8(a, c);
    }
    return;
  }
  int e = blockIdx.z;
  int nrows = cnt[e];
  int row0 = blockIdx.y * BM;
  if (row0 >= nrows) return;
  int col0 = blockIdx.x * BN;                 // in [0, 4096)
  int base = off[e];

  __shared__ unsigned short sA[2][BM][BK];
  __shared__ unsigned short sB[2][BN][BK];

  int srow = tid >> 3;                        // 0..31
  int dst8 = (tid & 7) * 8;                   // linear LDS chunk
  int src8 = ((tid & 7) ^ (srow & 7)) * 8;    // pre-swizzled global column

  const unsigned short* asrc[4];
  const unsigned short* bsrc[4];
#pragma unroll
  for (int i = 0; i < 4; i++) {
    int r = row0 + srow + 32 * i;
    int tok = (r < nrows) ? assign[base + r] : assign[base];
    asrc[i] = xb + (size_t)tok * D_DIM + src8;
    int wrow = (e << 12) + col0 + srow + 32 * i;
    bsrc[i] = wgu + (size_t)wrow * D_DIM + src8;
  }

  int wr = (tid >> 7) & 1, wc = (tid >> 6) & 1;
  int lane = tid & 63;
  int fr = lane & 15;
  int fk = (lane >> 4) * 8;
  int rx = (fr & 7) * 8;                      // read-side swizzle XOR

  f32x4 acc[4][4];
#pragma unroll
  for (int a = 0; a < 4; a++)
#pragma unroll
    for (int b = 0; b < 4; b++) acc[a][b] = (f32x4){0.f, 0.f, 0.f, 0.f};

#define STAGE(bf, k0)                                                       \
  _Pragma("unroll")                                                         \
  for (int i = 0; i < 4; i++) {                                             \
    gload_lds16(asrc[i] + (k0), &sA[bf][srow + 32 * i][dst8]);              \
    gload_lds16(bsrc[i] + (k0), &sB[bf][srow + 32 * i][dst8]);              \
  }
#define COMPUTE(bf)                                                         \
  _Pragma("unroll")                                                         \
  for (int ks = 0; ks < 2; ks++) {                                          \
    short8 af[4], bq[4];                                                    \
    int c = (ks * 32 + fk) ^ rx;                                            \
    _Pragma("unroll")                                                       \
    for (int mb = 0; mb < 4; mb++)                                          \
      af[mb] = *(const short8*)&sA[bf][wr * 64 + mb * 16 + fr][c];          \
    _Pragma("unroll")                                                       \
    for (int nb = 0; nb < 4; nb++)                                          \
      bq[nb] = *(const short8*)&sB[bf][wc * 64 + nb * 16 + fr][c];          \
    _Pragma("unroll")                                                       \
    for (int mb = 0; mb < 4; mb++)                                          \
      _Pragma("unroll")                                                     \
      for (int nb = 0; nb < 4; nb++)                                        \
        acc[mb][nb] = __builtin_amdgcn_mfma_f32_16x16x32_bf16(              \
            af[mb], bq[nb], acc[mb][nb], 0, 0, 0);                          \
  }

  STAGE(0, 0);
  __syncthreads();
  for (int k0 = 0; k0 < D_DIM - 128; k0 += 128) {
    STAGE(1, k0 + 64);  COMPUTE(0); __syncthreads();
    STAGE(0, k0 + 128); COMPUTE(1); __syncthreads();
  }
  STAGE(1, D_DIM - 64); COMPUTE(0); __syncthreads();
  COMPUTE(1);
#undef STAGE
#undef COMPUTE

  int rowlim = nrows - row0;
#pragma unroll
  for (int mb = 0; mb < 4; mb++)
#pragma unroll
    for (int r = 0; r < 4; r++) {
      int lrow = wr * 64 + mb * 16 + (lane >> 4) * 4 + r;
      if (lrow < rowlim) {
        size_t hrow = (size_t)(base + row0 + lrow);
#pragma unroll
        for (int nbp = 0; nbp < 2; nbp++) {
          float g = acc[mb][2 * nbp][r], u = acc[mb][2 * nbp + 1][r];
          float hv = g / (1.f + __expf(-g)) * u;     // silu(g)*u
          int hcol = (col0 >> 1) + wc * 32 + nbp * 16 + (lane & 15);
          hbuf[hrow * H_DIM + hcol] = f2bf(hv);
        }
      }
    }
}

// ---------- K4: GEMM2 + fused combine: out[tok] += w * (h @ Wd^T) -----------
// Each out element receives exactly 2 atomic contributions onto a zeroed
// buffer; IEEE fp add is commutative -> result is bitwise deterministic.
__global__ __launch_bounds__(256) void gemm_down(
    const unsigned short* __restrict__ hbuf,  // [N_ASSIGN, H] bf16
    const unsigned short* __restrict__ wd,    // [E*D, H] bf16
    const int* __restrict__ cnt, const int* __restrict__ off,
    const int* __restrict__ assign, const float* __restrict__ wassign,
    float* __restrict__ out) {                // [N_TOK, D] fp32 (pre-zeroed)
  int e = blockIdx.z;
  int nrows = cnt[e];
  int row0 = blockIdx.y * BM;
  if (row0 >= nrows) return;
  int col0 = blockIdx.x * BN;
  int base = off[e];

  __shared__ unsigned short sA[2][BM][BK];
  __shared__ unsigned short sB[2][BN][BK];

  int tid = threadIdx.x;
  int srow = tid >> 3;
  int dst8 = (tid & 7) * 8;
  int src8 = ((tid & 7) ^ (srow & 7)) * 8;

  const unsigned short* asrc[4];
  const unsigned short* bsrc[4];
#pragma unroll
  for (int i = 0; i < 4; i++) {
    int r = row0 + srow + 32 * i;
    int hrow = base + ((r < nrows) ? r : 0);
    asrc[i] = hbuf + (size_t)hrow * H_DIM + src8;
    int wrow = e * D_DIM + col0 + srow + 32 * i;
    bsrc[i] = wd + (size_t)wrow * H_DIM + src8;
  }

  int wr = (tid >> 7) & 1, wc = (tid >> 6) & 1;
  int lane = tid & 63;
  int fr = lane & 15;
  int fk = (lane >> 4) * 8;
  int rx = (fr & 7) * 8;

  f32x4 acc[4][4];
#pragma unroll
  for (int a = 0; a < 4; a++)
#pragma unroll
    for (int b = 0; b < 4; b++) acc[a][b] = (f32x4){0.f, 0.f, 0.f, 0.f};

#define STAGE(bf, k0)                                                       \
  _Pragma("unroll")                                                         \
  for (int i = 0; i < 4; i++) {                                             \
    gload_lds16(asrc[i] + (k0), &sA[bf][srow + 32 * i][dst8]);              \
    gload_lds16(bsrc[i] + (k0), &sB[bf][srow + 32 * i][dst8]);              \
  }
#define COMPUTE(bf)                                                         \
  _Pragma("unroll")                                                         \
  for (int ks = 0; ks < 2; ks++) {                                          \
    short8 af[4], bq[4];                                                    \
    int c = (ks * 32 + fk) ^ rx;                                            \
    _Pragma("unroll")                                                       \
    for (int mb = 0; mb < 4; mb++)                                          \
      af[mb] = *(const short8*)&sA[bf][wr * 64 + mb * 16 + fr][c];          \
    _Pragma("unroll")                                                       \
    for (int nb = 0; nb < 4; nb++)                                          \
      bq[nb] = *(const short8*)&sB[bf][wc * 64 + nb * 16 + fr][c];          \
    _Pragma("unroll")                                                       \
    for (int mb = 0; mb < 4; mb++)                                          \
      _Pragma("unroll")                                                     \
      for (int nb = 0; nb < 4; nb++)                                        \
        acc[mb][nb] = __builtin_amdgcn_mfma_f32_16x16x32_bf16(              \
            af[mb], bq[nb], acc[mb][nb], 0, 0, 0);                          \
  }

  STAGE(0, 0);
  __syncthreads();
  for (int k0 = 0; k0 < H_DIM - 128; k0 += 128) {
    STAGE(1, k0 + 64);  COMPUTE(0); __syncthreads();
    STAGE(0, k0 + 128); COMPUTE(1); __syncthreads();
  }
  STAGE(1, H_DIM - 64); COMPUTE(0); __syncthreads();
  COMPUTE(1);
#undef STAGE
#undef COMPUTE

  int rowlim = nrows - row0;
#pragma unroll
  for (int mb = 0; mb < 4; mb++)
#pragma unroll
    for (int r = 0; r < 4; r++) {
      int lrow = wr * 64 + mb * 16 + (lane >> 4) * 4 + r;
      if (lrow < rowlim) {
        int grow = base + row0 + lrow;
        int tok = assign[grow];
        float w = wassign[grow];
        float* op = out + (size_t)tok * D_DIM + col0 + wc * 64 + fr;
#pragma unroll
        for (int nb = 0; nb < 4; nb++)
          atomicAdd(op + nb * 16, w * acc[mb][nb][r]);
      }
    }
}

extern "C" void kernel_launch(void* const* d_in, const int* in_sizes, int n_in,
                              void* d_out, int out_size, void* d_ws, size_t ws_size,
                              hipStream_t stream) {
  const float* x  = (const float*)d_in[0];
  const float* rw = (const float*)d_in[1];
  const float* rb = (const float*)d_in[2];
  const float* wg = (const float*)d_in[3];
  const float* wu = (const float*)d_in[4];
  const float* wd = (const float*)d_in[5];
  float* out = (float*)d_out;

  char* ws = (char*)d_ws;
  size_t o = 0;
  auto alloc = [&](size_t b) { char* p = ws + o; o += (b + 255) & ~(size_t)255; return p; };
  unsigned short* xb  = (unsigned short*)alloc((size_t)N_TOK * D_DIM * 2);           // 16.8 MB
  unsigned short* wgu = (unsigned short*)alloc((size_t)N_EXP * 4096 * D_DIM * 2);    // 67.1 MB
  unsigned short* wdb = (unsigned short*)alloc((size_t)N_EXP * D_DIM * H_DIM * 2);   // 33.6 MB
  unsigned short* hb  = (unsigned short*)alloc((size_t)N_ASSIGN * H_DIM * 2);        // 67.1 MB
  int*    assign  = (int*)alloc(N_ASSIGN * 4);
  float*  wassign = (float*)alloc(N_ASSIGN * 4);
  int2*   tiidx   = (int2*)alloc(N_TOK * 8);
  float2* tiw     = (float2*)alloc(N_TOK * 8);
  int*    cnt     = (int*)alloc(64);
  int*    off     = (int*)alloc(64);

  hipMemsetAsync(out, 0, (size_t)out_size * 4, stream);
  router_prep_kernel<<<2048 + 16384, 256, 0, stream>>>(
      x, rw, rb, wg, wu, xb, wgu, tiidx, tiw);
  plan_kernel<<<1, 256, 0, stream>>>(tiidx, tiw, cnt, off, assign, wassign);
  gemm_gateup<<<dim3(4096 / BN, N_TOK / BM, N_EXP + 1), 256, 0, stream>>>(
      xb, wgu, wd, wdb, cnt, off, assign, hb);
  gemm_down<<<dim3(D_DIM / BN, N_TOK / BM, N_EXP), 256, 0, stream>>>(
      hb, wdb, cnt, off, assign, wassign, out);
}

// Round 10
// 354.706 us; speedup vs baseline: 1.2090x; 1.1080x over previous
//
#include <hip/hip_runtime.h>
#include <hip/hip_bf16.h>
#include <stdint.h>

// SparseMoE top-2/8, N=8192, D=1024, H=2048, fp32 in/out.
// R10: exact revert to R6 (the measured optimum, 350us). R7/R8 schedule
//      rewrites and R9 atomic-combine all regressed; the 2-phase dbuf +
//      both-sides-swizzle GEMMs here run ~690 TF, at/above the documented
//      2-phase structural ceiling (m230/m248). Pipeline: atomic-free router
//      (+wgu convert fused), single-block scan plan, gateup GEMM (+wd convert
//      fused as z==8), down GEMM, streaming combine.

#define N_TOK 8192
#define D_DIM 1024
#define H_DIM 2048
#define N_EXP 8
#define N_ASSIGN (N_TOK * 2)
#define BM 128
#define BN 128
#define BK 64

typedef __attribute__((ext_vector_type(8))) short short8;   // bf16x8
typedef __attribute__((ext_vector_type(4))) float f32x4;    // MFMA acc frag

__device__ __forceinline__ unsigned short f2bf(float f) {
  union { float f; unsigned int u; } v; v.f = f;
  unsigned int r = v.u + 0x7fffu + ((v.u >> 16) & 1u);  // RTNE
  return (unsigned short)(r >> 16);
}
__device__ __forceinline__ float bf2f(unsigned short u) {
  union { float f; unsigned int u; } v; v.u = ((unsigned int)u) << 16; return v.f;
}
__device__ __forceinline__ short8 pack8(float4 a, float4 b) {
  short8 o;
  o[0] = (short)f2bf(a.x); o[1] = (short)f2bf(a.y);
  o[2] = (short)f2bf(a.z); o[3] = (short)f2bf(a.w);
  o[4] = (short)f2bf(b.x); o[5] = (short)f2bf(b.y);
  o[6] = (short)f2bf(b.z); o[7] = (short)f2bf(b.w);
  return o;
}
__device__ __forceinline__ void gload_lds16(const void* g, void* l) {
  __builtin_amdgcn_global_load_lds((const __attribute__((address_space(1))) void*)g,
                                   (__attribute__((address_space(3))) void*)l, 16, 0, 0);
}

// ---------- K1: router (blocks [0,2048)) + wgu convert (blocks [2048,18432))
// NO atomics: emits (e1,e2) + normalized weights per token only.
__global__ __launch_bounds__(256) void router_prep_kernel(
    const float* __restrict__ x, const float* __restrict__ rw,
    const float* __restrict__ rb,
    const float* __restrict__ wg, const float* __restrict__ wu,
    unsigned short* __restrict__ xb, unsigned short* __restrict__ wgu,
    int2* __restrict__ tiidx, float2* __restrict__ tiw) {
  int b = blockIdx.x;
  int tid = threadIdx.x;
  if (b >= 2048) {
    // wgu convert: interleave gate/up at 16-row granularity -> [E][4096][D]
    int idx = b - 2048;                      // 0..16383
    int up = idx >> 13;                      // 0 = gate, 1 = up
    size_t i = (((size_t)(idx & 8191)) * 256 + tid) * 8;
    const float* src = up ? wu : wg;
    float4 a = *(const float4*)(src + i);
    float4 c = *(const float4*)(src + i + 4);
    int j = (int)(i >> 10);                  // source row = e*H + jj
    int e = j >> 11;
    int jj = j & (H_DIM - 1);
    int n = ((jj >> 4) << 5) + (up ? 16 : 0) + (jj & 15);
    size_t di = (((size_t)(e << 12) + n) << 10) + (i & 1023);
    *(short8*)(wgu + di) = pack8(a, c);
    return;
  }

  __shared__ float sw[N_EXP][D_DIM];          // 32 KB router weights
  for (int i = tid * 4; i < N_EXP * D_DIM; i += 1024)
    *(float4*)&sw[0][i] = *(const float4*)(rw + i);
  __syncthreads();

  int wave = tid >> 6, lane = tid & 63;
  int t = b * 4 + wave;
  const float2* xr = (const float2*)(x + (size_t)t * D_DIM);
  float2 xs[8];
#pragma unroll
  for (int j = 0; j < 8; j++) xs[j] = xr[lane + 64 * j];
  unsigned int* xbo = (unsigned int*)(xb + (size_t)t * D_DIM);
#pragma unroll
  for (int j = 0; j < 8; j++) {
    unsigned int pk = ((unsigned int)f2bf(xs[j].y) << 16) | (unsigned int)f2bf(xs[j].x);
    xbo[lane + 64 * j] = pk;
  }

  float logit[N_EXP];
#pragma unroll
  for (int e = 0; e < N_EXP; e++) {
    float acc = 0.f;
    const float2* swe = (const float2*)sw[e];
#pragma unroll
    for (int j = 0; j < 8; j++) {
      float2 w2 = swe[lane + 64 * j];
      acc += xs[j].x * w2.x + xs[j].y * w2.y;
    }
#pragma unroll
    for (int off = 32; off; off >>= 1) acc += __shfl_xor(acc, off);
    logit[e] = acc + rb[e];
  }
  if (lane == 0) {
    float m = logit[0];
#pragma unroll
    for (int e = 1; e < N_EXP; e++) m = fmaxf(m, logit[e]);
    float p[N_EXP], S = 0.f;
#pragma unroll
    for (int e = 0; e < N_EXP; e++) { p[e] = expf(logit[e] - m); S += p[e]; }
#pragma unroll
    for (int e = 0; e < N_EXP; e++) p[e] /= S;
    int i1 = 0; float v1 = p[0];
#pragma unroll
    for (int e = 1; e < N_EXP; e++) if (p[e] > v1) { v1 = p[e]; i1 = e; }
    int i2 = -1; float v2 = -1.f;
#pragma unroll
    for (int e = 0; e < N_EXP; e++) if (e != i1 && p[e] > v2) { v2 = p[e]; i2 = e; }
    float inv = 1.f / (v1 + v2 + 1e-9f);
    tiidx[t] = make_int2(i1, i2);
    tiw[t] = make_float2(v1 * inv, v2 * inv);
  }
}

// ---------- K2: plan = histogram + scan + slot assignment, one block, 0 atomics
__global__ __launch_bounds__(256) void plan_kernel(
    const int2* __restrict__ tiidx, int* __restrict__ cnt,
    int* __restrict__ off, int* __restrict__ assign, int2* __restrict__ trows) {
  __shared__ int sh[256][N_EXP + 1];
  __shared__ int soff[N_EXP];
  int tid = threadIdx.x;
  int t0 = tid * 32;

#pragma unroll
  for (int e = 0; e < N_EXP; e++) sh[tid][e] = 0;
  for (int i = 0; i < 32; i++) {
    int2 te = tiidx[t0 + i];
    sh[tid][te.x]++;
    sh[tid][te.y]++;
  }
  int oc[N_EXP];
#pragma unroll
  for (int e = 0; e < N_EXP; e++) oc[e] = sh[tid][e];
  __syncthreads();

  for (int s = 1; s < 256; s <<= 1) {
    int v[N_EXP];
#pragma unroll
    for (int e = 0; e < N_EXP; e++) v[e] = (tid >= s) ? sh[tid - s][e] : 0;
    __syncthreads();
#pragma unroll
    for (int e = 0; e < N_EXP; e++) sh[tid][e] += v[e];
    __syncthreads();
  }

  int ex[N_EXP];
#pragma unroll
  for (int e = 0; e < N_EXP; e++) ex[e] = sh[tid][e] - oc[e];
  if (tid == 0) {
    int a = 0;
    for (int e = 0; e < N_EXP; e++) {
      int tot = sh[255][e];
      soff[e] = a; off[e] = a; cnt[e] = tot; a += tot;
    }
    off[N_EXP] = a;
  }
  __syncthreads();
#pragma unroll
  for (int e = 0; e < N_EXP; e++) sh[tid][e] = ex[e];
  __syncthreads();

  for (int i = 0; i < 32; i++) {
    int t = t0 + i;
    int2 te = tiidx[t];
    int r1 = soff[te.x] + sh[tid][te.x]++;
    int r2 = soff[te.y] + sh[tid][te.y]++;
    assign[r1] = t;
    assign[r2] = t;
    trows[t] = make_int2(r1, r2);
  }
}

// ---------- K3: GEMM1 (z<8) fused gate+up  |  wd convert (z==8) --------------
__global__ __launch_bounds__(256) void gemm_gateup(
    const unsigned short* __restrict__ xb,    // [N_TOK, D] bf16
    const unsigned short* __restrict__ wgu,   // [E*4096, D] bf16 interleaved
    const float* __restrict__ wd,             // [E*D, H] fp32 (for convert slice)
    unsigned short* __restrict__ wdb,         // [E*D, H] bf16 out
    const int* __restrict__ cnt, const int* __restrict__ off,
    const int* __restrict__ assign,
    unsigned short* __restrict__ hbuf) {      // [N_ASSIGN, H] bf16
  int tid = threadIdx.x;
  if (blockIdx.z == 8) {
    size_t b0 = ((size_t)(blockIdx.x + 32 * blockIdx.y)) * 8192;
#pragma unroll
    for (int it = 0; it < 4; it++) {
      size_t i = b0 + ((size_t)it * 256 + tid) * 8;
      float4 a = *(const float4*)(wd + i);
      float4 c = *(const float4*)(wd + i + 4);
      *(short8*)(wdb + i) = pack8(a, c);
    }
    return;
  }
  int e = blockIdx.z;
  int nrows = cnt[e];
  int row0 = blockIdx.y * BM;
  if (row0 >= nrows) return;
  int col0 = blockIdx.x * BN;                 // in [0, 4096)
  int base = off[e];

  __shared__ unsigned short sA[2][BM][BK];
  __shared__ unsigned short sB[2][BN][BK];

  int srow = tid >> 3;                        // 0..31
  int dst8 = (tid & 7) * 8;                   // linear LDS chunk
  int src8 = ((tid & 7) ^ (srow & 7)) * 8;    // pre-swizzled global column

  const unsigned short* asrc[4];
  const unsigned short* bsrc[4];
#pragma unroll
  for (int i = 0; i < 4; i++) {
    int r = row0 + srow + 32 * i;
    int tok = (r < nrows) ? assign[base + r] : assign[base];
    asrc[i] = xb + (size_t)tok * D_DIM + src8;
    int wrow = (e << 12) + col0 + srow + 32 * i;
    bsrc[i] = wgu + (size_t)wrow * D_DIM + src8;
  }

  int wr = (tid >> 7) & 1, wc = (tid >> 6) & 1;
  int lane = tid & 63;
  int fr = lane & 15;
  int fk = (lane >> 4) * 8;
  int rx = (fr & 7) * 8;                      // read-side swizzle XOR

  f32x4 acc[4][4];
#pragma unroll
  for (int a = 0; a < 4; a++)
#pragma unroll
    for (int b = 0; b < 4; b++) acc[a][b] = (f32x4){0.f, 0.f, 0.f, 0.f};

#define STAGE(bf, k0)                                                       \
  _Pragma("unroll")                                                         \
  for (int i = 0; i < 4; i++) {                                             \
    gload_lds16(asrc[i] + (k0), &sA[bf][srow + 32 * i][dst8]);              \
    gload_lds16(bsrc[i] + (k0), &sB[bf][srow + 32 * i][dst8]);              \
  }
#define COMPUTE(bf)                                                         \
  _Pragma("unroll")                                                         \
  for (int ks = 0; ks < 2; ks++) {                                          \
    short8 af[4], bq[4];                                                    \
    int c = (ks * 32 + fk) ^ rx;                                            \
    _Pragma("unroll")                                                       \
    for (int mb = 0; mb < 4; mb++)                                          \
      af[mb] = *(const short8*)&sA[bf][wr * 64 + mb * 16 + fr][c];          \
    _Pragma("unroll")                                                       \
    for (int nb = 0; nb < 4; nb++)                                          \
      bq[nb] = *(const short8*)&sB[bf][wc * 64 + nb * 16 + fr][c];          \
    _Pragma("unroll")                                                       \
    for (int mb = 0; mb < 4; mb++)                                          \
      _Pragma("unroll")                                                     \
      for (int nb = 0; nb < 4; nb++)                                        \
        acc[mb][nb] = __builtin_amdgcn_mfma_f32_16x16x32_bf16(              \
            af[mb], bq[nb], acc[mb][nb], 0, 0, 0);                          \
  }

  STAGE(0, 0);
  __syncthreads();
  for (int k0 = 0; k0 < D_DIM - 128; k0 += 128) {
    STAGE(1, k0 + 64);  COMPUTE(0); __syncthreads();
    STAGE(0, k0 + 128); COMPUTE(1); __syncthreads();
  }
  STAGE(1, D_DIM - 64); COMPUTE(0); __syncthreads();
  COMPUTE(1);
#undef STAGE
#undef COMPUTE

  int rowlim = nrows - row0;
#pragma unroll
  for (int mb = 0; mb < 4; mb++)
#pragma unroll
    for (int r = 0; r < 4; r++) {
      int lrow = wr * 64 + mb * 16 + (lane >> 4) * 4 + r;
      if (lrow < rowlim) {
        size_t hrow = (size_t)(base + row0 + lrow);
#pragma unroll
        for (int nbp = 0; nbp < 2; nbp++) {
          float g = acc[mb][2 * nbp][r], u = acc[mb][2 * nbp + 1][r];
          float hv = g / (1.f + __expf(-g)) * u;     // silu(g)*u
          int hcol = (col0 >> 1) + wc * 32 + nbp * 16 + (lane & 15);
          hbuf[hrow * H_DIM + hcol] = f2bf(hv);
        }
      }
    }
}

// ---------- K4: GEMM2 e_out = h @ Wd^T ---------------------------------------
__global__ __launch_bounds__(256) void gemm_down(
    const unsigned short* __restrict__ hbuf,  // [N_ASSIGN, H] bf16
    const unsigned short* __restrict__ wd,    // [E*D, H] bf16
    const int* __restrict__ cnt, const int* __restrict__ off,
    unsigned short* __restrict__ eo) {        // [N_ASSIGN, D] bf16
  int e = blockIdx.z;
  int nrows = cnt[e];
  int row0 = blockIdx.y * BM;
  if (row0 >= nrows) return;
  int col0 = blockIdx.x * BN;
  int base = off[e];

  __shared__ unsigned short sA[2][BM][BK];
  __shared__ unsigned short sB[2][BN][BK];

  int tid = threadIdx.x;
  int srow = tid >> 3;
  int dst8 = (tid & 7) * 8;
  int src8 = ((tid & 7) ^ (srow & 7)) * 8;

  const unsigned short* asrc[4];
  const unsigned short* bsrc[4];
#pragma unroll
  for (int i = 0; i < 4; i++) {
    int r = row0 + srow + 32 * i;
    int hrow = base + ((r < nrows) ? r : 0);
    asrc[i] = hbuf + (size_t)hrow * H_DIM + src8;
    int wrow = e * D_DIM + col0 + srow + 32 * i;
    bsrc[i] = wd + (size_t)wrow * H_DIM + src8;
  }

  int wr = (tid >> 7) & 1, wc = (tid >> 6) & 1;
  int lane = tid & 63;
  int fr = lane & 15;
  int fk = (lane >> 4) * 8;
  int rx = (fr & 7) * 8;

  f32x4 acc[4][4];
#pragma unroll
  for (int a = 0; a < 4; a++)
#pragma unroll
    for (int b = 0; b < 4; b++) acc[a][b] = (f32x4){0.f, 0.f, 0.f, 0.f};

#define STAGE(bf, k0)                                                       \
  _Pragma("unroll")                                                         \
  for (int i = 0; i < 4; i++) {                                             \
    gload_lds16(asrc[i] + (k0), &sA[bf][srow + 32 * i][dst8]);              \
    gload_lds16(bsrc[i] + (k0), &sB[bf][srow + 32 * i][dst8]);              \
  }
#define COMPUTE(bf)                                                         \
  _Pragma("unroll")                                                         \
  for (int ks = 0; ks < 2; ks++) {                                          \
    short8 af[4], bq[4];                                                    \
    int c = (ks * 32 + fk) ^ rx;                                            \
    _Pragma("unroll")                                                       \
    for (int mb = 0; mb < 4; mb++)                                          \
      af[mb] = *(const short8*)&sA[bf][wr * 64 + mb * 16 + fr][c];          \
    _Pragma("unroll")                                                       \
    for (int nb = 0; nb < 4; nb++)                                          \
      bq[nb] = *(const short8*)&sB[bf][wc * 64 + nb * 16 + fr][c];          \
    _Pragma("unroll")                                                       \
    for (int mb = 0; mb < 4; mb++)                                          \
      _Pragma("unroll")                                                     \
      for (int nb = 0; nb < 4; nb++)                                        \
        acc[mb][nb] = __builtin_amdgcn_mfma_f32_16x16x32_bf16(              \
            af[mb], bq[nb], acc[mb][nb], 0, 0, 0);                          \
  }

  STAGE(0, 0);
  __syncthreads();
  for (int k0 = 0; k0 < H_DIM - 128; k0 += 128) {
    STAGE(1, k0 + 64);  COMPUTE(0); __syncthreads();
    STAGE(0, k0 + 128); COMPUTE(1); __syncthreads();
  }
  STAGE(1, H_DIM - 64); COMPUTE(0); __syncthreads();
  COMPUTE(1);
#undef STAGE
#undef COMPUTE

  int rowlim = nrows - row0;
#pragma unroll
  for (int mb = 0; mb < 4; mb++)
#pragma unroll
    for (int r = 0; r < 4; r++) {
      int lrow = wr * 64 + mb * 16 + (lane >> 4) * 4 + r;
      if (lrow < rowlim) {
        size_t orow = (size_t)(base + row0 + lrow);
#pragma unroll
        for (int nb = 0; nb < 4; nb++)
          eo[orow * D_DIM + col0 + wc * 64 + nb * 16 + (lane & 15)] = f2bf(acc[mb][nb][r]);
      }
    }
}

// ---------- K5: combine out[t] = w1*eo[r1] + w2*eo[r2] -----------------------
__global__ __launch_bounds__(256) void combine_kernel(
    const unsigned short* __restrict__ eo, const int2* __restrict__ trows,
    const float2* __restrict__ tiw, float* __restrict__ out) {
  int t = blockIdx.x * 2 + (threadIdx.x >> 7);
  int l = threadIdx.x & 127;
  int c = l * 8;
  int2 r = trows[t];
  float2 w = tiw[t];
  short8 a = *(const short8*)&eo[(size_t)r.x * D_DIM + c];
  short8 b = *(const short8*)&eo[(size_t)r.y * D_DIM + c];
  float4 o0, o1;
  o0.x = w.x * bf2f((unsigned short)a[0]) + w.y * bf2f((unsigned short)b[0]);
  o0.y = w.x * bf2f((unsigned short)a[1]) + w.y * bf2f((unsigned short)b[1]);
  o0.z = w.x * bf2f((unsigned short)a[2]) + w.y * bf2f((unsigned short)b[2]);
  o0.w = w.x * bf2f((unsigned short)a[3]) + w.y * bf2f((unsigned short)b[3]);
  o1.x = w.x * bf2f((unsigned short)a[4]) + w.y * bf2f((unsigned short)b[4]);
  o1.y = w.x * bf2f((unsigned short)a[5]) + w.y * bf2f((unsigned short)b[5]);
  o1.z = w.x * bf2f((unsigned short)a[6]) + w.y * bf2f((unsigned short)b[6]);
  o1.w = w.x * bf2f((unsigned short)a[7]) + w.y * bf2f((unsigned short)b[7]);
  *(float4*)&out[(size_t)t * D_DIM + c] = o0;
  *(float4*)&out[(size_t)t * D_DIM + c + 4] = o1;
}

extern "C" void kernel_launch(void* const* d_in, const int* in_sizes, int n_in,
                              void* d_out, int out_size, void* d_ws, size_t ws_size,
                              hipStream_t stream) {
  const float* x  = (const float*)d_in[0];
  const float* rw = (const float*)d_in[1];
  const float* rb = (const float*)d_in[2];
  const float* wg = (const float*)d_in[3];
  const float* wu = (const float*)d_in[4];
  const float* wd = (const float*)d_in[5];
  float* out = (float*)d_out;

  char* ws = (char*)d_ws;
  size_t o = 0;
  auto alloc = [&](size_t b) { char* p = ws + o; o += (b + 255) & ~(size_t)255; return p; };
  unsigned short* xb  = (unsigned short*)alloc((size_t)N_TOK * D_DIM * 2);           // 16.8 MB
  unsigned short* wgu = (unsigned short*)alloc((size_t)N_EXP * 4096 * D_DIM * 2);    // 67.1 MB
  unsigned short* wdb = (unsigned short*)alloc((size_t)N_EXP * D_DIM * H_DIM * 2);   // 33.6 MB
  unsigned short* hb  = (unsigned short*)alloc((size_t)N_ASSIGN * H_DIM * 2);        // 67.1 MB
  unsigned short* eob = (unsigned short*)alloc((size_t)N_ASSIGN * D_DIM * 2);        // 33.6 MB
  int*    assign = (int*)alloc(N_ASSIGN * 4);
  int2*   tiidx  = (int2*)alloc(N_TOK * 8);
  float2* tiw    = (float2*)alloc(N_TOK * 8);
  int2*   trows  = (int2*)alloc(N_TOK * 8);
  int*    cnt    = (int*)alloc(64);
  int*    off    = (int*)alloc(64);

  router_prep_kernel<<<2048 + 16384, 256, 0, stream>>>(
      x, rw, rb, wg, wu, xb, wgu, tiidx, tiw);
  plan_kernel<<<1, 256, 0, stream>>>(tiidx, cnt, off, assign, trows);
  gemm_gateup<<<dim3(4096 / BN, N_TOK / BM, N_EXP + 1), 256, 0, stream>>>(
      xb, wgu, wd, wdb, cnt, off, assign, hb);
  gemm_down<<<dim3(D_DIM / BN, N_TOK / BM, N_EXP), 256, 0, stream>>>(
      hb, wdb, cnt, off, eob);
  combine_kernel<<<N_TOK / 2, 256, 0, stream>>>(eob, trows, tiw, out);
}